// Round 13
// baseline (26.386 us; speedup 1.0000x reference)
//
#include <hip/hip_runtime.h>

#define NS 384
#define NT 384
#define D  256
#define NTILE 24
#define NBLK 48             // (tile 0..23) x (half 0..1)
#define RNS 408             // Rn row stride in ushort (816 B = 51*16, ~2-way banks)
#define STB 784             // St row stride in BYTES (392 ushort = 49*16)
#define MAGIC 0x7A3F19C5u
#define SPIN_MAX (1 << 22)

typedef __attribute__((ext_vector_type(8))) short bf16x8;
typedef __attribute__((ext_vector_type(4))) float f32x4;

__device__ __forceinline__ unsigned short f2bf(float f) {   // RNE f32 -> bf16
    unsigned u = __float_as_uint(f);
    return (unsigned short)((u + 0x7FFFu + ((u >> 16) & 1u)) >> 16);
}
__device__ __forceinline__ float bf2f(unsigned short h) {
    return __uint_as_float(((unsigned)h) << 16);
}
// 8 consecutive f32 -> bf16x8 frag; accumulates sum of squares of ROUNDED values
__device__ __forceinline__ bf16x8 load8_bf(const float* __restrict__ p, float& ss) {
    const float4 f0 = *(const float4*)p;
    const float4 f1 = *(const float4*)(p + 4);
    const float vf[8] = {f0.x, f0.y, f0.z, f0.w, f1.x, f1.y, f1.z, f1.w};
    bf16x8 r;
#pragma unroll
    for (int j = 0; j < 8; ++j) {
        const unsigned short h = f2bf(vf[j]);
        r[j] = (short)h;
        const float v = bf2f(h);
        ss += v * v;
    }
    return r;
}

// One node, 48 blocks x 512 threads: block = (t-tile, d-half of 128 cols).
// Phase 1: 8 waves x 3 i-tiles: in-reg bf16 cast -> dot MFMA -> rn -> LDS Rn;
//   scatter this half's 128-d transposed src slice to LDS St (XOR-swizzled,
//   write/read same involution); group terms (R11-proven live-dot sequence)
//   partitioned j<12 / j>=12 across halves -> each (t,g) exactly once.
// Phase 2: W-GEMM (K=384) fully from LDS; ||At*t - W||^2 vs f32 trgt.
// Finish: tagged-slot publish (MAGIC|f32, never reset, poison-immune);
// block 47 gathers 48 slots in fixed order -> deterministic scalar.
__global__ __launch_bounds__(512) void k_one(
        const float* __restrict__ src, const float* __restrict__ trgt,
        unsigned long long* __restrict__ slots, float* __restrict__ out) {
    const int b = blockIdx.x, tid = threadIdx.x;
    const int w = tid >> 6, l = tid & 63;
    const int lc = l & 15, lr4 = l >> 4;
    const int tile = b >> 1, half = b & 1;
    const int T0 = tile * 16;

    __shared__ unsigned short Rn[16][RNS];          // rn bf16 [16 t][384 i]
    __shared__ unsigned short St[128 * (STB / 2)];  // srcT half [128 d][384 i]
    __shared__ float4 Glds[8][16];
    __shared__ float AtP[8][16], GrpP[8][16], LossP[8][16];
    __shared__ float At16[16];
    __shared__ float Red[NBLK];

    char* stb = (char*)&St[0];

    // trgt frags + nt2 of rounded rows (per-wave redundant, cheap)
    bf16x8 at[8]; float nt2p = 0.f;
#pragma unroll
    for (int kk = 0; kk < 8; ++kk)
        at[kk] = load8_bf(&trgt[(T0 + lc) * D + kk * 32 + lr4 * 8], nt2p);
    nt2p += __shfl_xor(nt2p, 16, 64);
    nt2p += __shfl_xor(nt2p, 32, 64);               // lane: nt2 of t-row lc

    float avr[4] = {0.f, 0.f, 0.f, 0.f};
    float grr[4] = {0.f, 0.f, 0.f, 0.f};

#pragma unroll
    for (int m = 0; m < 3; ++m) {                   // wave's i-tiles: w, w+8, w+16
        const int j = w + 8 * m, i0 = 16 * j;
        bf16x8 bs[8]; float ns2p = 0.f;
#pragma unroll
        for (int kk = 0; kk < 8; ++kk)
            bs[kk] = load8_bf(&src[(i0 + lc) * D + kk * 32 + lr4 * 8], ns2p);
        ns2p += __shfl_xor(ns2p, 16, 64);
        ns2p += __shfl_xor(ns2p, 32, 64);           // lane: ns2 of src-row lc

        f32x4 acc = {0.f, 0.f, 0.f, 0.f};           // dot[t-row][i-col]
#pragma unroll
        for (int kk = 0; kk < 8; ++kk)
            acc = __builtin_amdgcn_mfma_f32_16x16x32_bf16(at[kk], bs[kk], acc, 0, 0, 0);

        // ---- scatter this half's d-rows of srcT into St (swizzled) ----
        {
            const int cb = ((i0 + lc) * 2) ^ (lr4 << 5);   // swz = ((row>>3)&3)<<5 = lr4<<5
#pragma unroll
            for (int q = 0; q < 4; ++q) {
                const int kk = half * 4 + q;
                const int r0 = q * 32 + lr4 * 8;           // local d row base
                bf16x8 bq = bs[0];
                switch (kk) {                              // static-indexed pick
                    case 0: bq = bs[0]; break; case 1: bq = bs[1]; break;
                    case 2: bq = bs[2]; break; case 3: bq = bs[3]; break;
                    case 4: bq = bs[4]; break; case 5: bq = bs[5]; break;
                    case 6: bq = bs[6]; break; default: bq = bs[7]; break;
                }
#pragma unroll
                for (int jj = 0; jj < 8; ++jj)
                    *(unsigned short*)(stb + (r0 + jj) * STB + cb) =
                        (unsigned short)bq[jj];
            }
        }

        const bool doGrp = half ? (j >= 12) : (j < 12);    // each i-tile once grid-wide
        if (doGrp) {                                 // local 16x16 Gram (A==B)
            f32x4 g = {0.f, 0.f, 0.f, 0.f};
#pragma unroll
            for (int kk = 0; kk < 8; ++kk)
                g = __builtin_amdgcn_mfma_f32_16x16x32_bf16(bs[kk], bs[kk], g, 0, 0, 0);
            if (lr4 == (lc >> 2))                    // diag-block holder lanes
                Glds[w][lc] = make_float4(g[0], g[1], g[2], g[3]);
        }

        const int lbase = (l & 48) | (lc & 12);
#pragma unroll
        for (int r = 0; r < 4; ++r) {
            const int ri = lr4 * 4 + r;
            const float nt2v = __shfl(nt2p, ri, 64);
            const float dotv = acc[r];
            const float n2 = nt2v + ns2p - 2.f * dotv;   // norms ~22, EPS never binds
            const unsigned short rbits = f2bf(rsqrtf(n2));
            const float rnf = bf2f(rbits);           // rounded rn == W operand
            Rn[ri][i0 + lc] = rbits;
            avr[r] += rnf;
            if (doGrp) {                             // R11-proven group sequence
                const float4 gl = Glds[w][lc];       // G[group rows][col lc]
                const float rn0 = __shfl(rnf, lbase | 0, 64);
                const float rn1 = __shfl(rnf, lbase | 1, 64);
                const float rn2 = __shfl(rnf, lbase | 2, 64);
                const float rn3 = __shfl(rnf, lbase | 3, 64);
                const float R = rn0 + rn1 + rn2 + rn3;
                const float z = gl.x * rn0 + gl.y * rn1 + gl.z * rn2 + gl.w * rn3;
                float pv = rnf * dotv;
                pv += __shfl_xor(pv, 1, 64); pv += __shfl_xor(pv, 2, 64);
                float qv = rnf * z;
                qv += __shfl_xor(qv, 1, 64); qv += __shfl_xor(qv, 2, 64);
                float gval = nt2v * R * R - 2.f * R * pv + qv;   // ||S_g||^2
                gval += __shfl_xor(gval, 4, 64);
                gval += __shfl_xor(gval, 8, 64);     // wave's 4 groups
                grr[r] += gval;
            }
        }
    }

#pragma unroll
    for (int r = 0; r < 4; ++r) {                    // At over 16 cols
        float v = avr[r];
        v += __shfl_xor(v, 1, 64); v += __shfl_xor(v, 2, 64);
        v += __shfl_xor(v, 4, 64); v += __shfl_xor(v, 8, 64);
        if (lc == 0) { AtP[w][lr4 * 4 + r] = v; GrpP[w][lr4 * 4 + r] = grr[r]; }
    }
    __syncthreads();                                 // Rn / St / AtP / GrpP done
    if (tid < 16)
        At16[tid] = AtP[0][tid] + AtP[1][tid] + AtP[2][tid] + AtP[3][tid]
                  + AtP[4][tid] + AtP[5][tid] + AtP[6][tid] + AtP[7][tid];

    // -------- Phase 2: W-GEMM from LDS --------
    bf16x8 afW[12];
#pragma unroll
    for (int kk = 0; kk < 12; ++kk)
        afW[kk] = *(const bf16x8*)&Rn[lc][kk * 32 + lr4 * 8];

    const int n = w * 16 + lc;                       // local d row/col
    const int swzr = ((n >> 3) & 3) << 5;
    const char* bb = stb + n * STB;
    f32x4 wacc = {0.f, 0.f, 0.f, 0.f};               // W[t][half*128+n]
#pragma unroll
    for (int kk = 0; kk < 12; ++kk) {
        const bf16x8 bf = *(const bf16x8*)(bb + ((kk * 64 + lr4 * 16) ^ swzr));
        wacc = __builtin_amdgcn_mfma_f32_16x16x32_bf16(afW[kk], bf, wacc, 0, 0, 0);
    }
    __syncthreads();                                 // At16 ready

#pragma unroll
    for (int r = 0; r < 4; ++r) {
        const int ri = lr4 * 4 + r;
        const float tf = trgt[(T0 + ri) * D + half * 128 + n];   // f32 exact
        const float S = At16[ri] * tf - wacc[r];
        float v = S * S;
        v += __shfl_xor(v, 1, 64); v += __shfl_xor(v, 2, 64);
        v += __shfl_xor(v, 4, 64); v += __shfl_xor(v, 8, 64);
        if (lc == 0) LossP[w][ri] = v;
    }
    __syncthreads();

    if (tid == 0) {                                  // publish tagged partial
        double tot = 0.0;
        float gg = 0.f;
#pragma unroll
        for (int t = 0; t < 16; ++t) {
#pragma unroll
            for (int q = 0; q < 8; ++q) {
                tot += (double)LossP[q][t];
                gg  += GrpP[q][t];
            }
        }
        tot -= 2.0 * (double)gg;
        const unsigned long long pk = ((unsigned long long)MAGIC << 32)
                                    | (unsigned long long)__float_as_uint((float)tot);
        __hip_atomic_store(&slots[b], pk, __ATOMIC_RELEASE,
                           __HIP_MEMORY_SCOPE_AGENT);
    }

    if (b == NBLK - 1) {                             // gather: fixed-order sum
        if (tid < NBLK) {
            unsigned long long v = 0ull;
            int spins = 0;
            for (;;) {
                v = __hip_atomic_load(&slots[tid], __ATOMIC_ACQUIRE,
                                      __HIP_MEMORY_SCOPE_AGENT);
                if ((unsigned)(v >> 32) == MAGIC) break;
                if (++spins > SPIN_MAX) break;       // fail loud, never hang
                __builtin_amdgcn_s_sleep(4);
            }
            Red[tid] = __uint_as_float((unsigned)(v & 0xFFFFFFFFull));
        }
        __syncthreads();
        if (tid == 0) {
            double tot = 0.0;
            for (int i = 0; i < NBLK; ++i) tot += (double)Red[i];
            out[0] = (float)(tot / ((double)NS * (double)NS * (double)NT));
        }
    }
}

extern "C" void kernel_launch(void* const* d_in, const int* in_sizes, int n_in,
                              void* d_out, int out_size, void* d_ws, size_t ws_size,
                              hipStream_t stream) {
    const float* src  = (const float*)d_in[0];   // [384,256] f32
    const float* trgt = (const float*)d_in[1];   // [384,256] f32
    unsigned long long* slots = (unsigned long long*)d_ws;   // [48] tagged partials
    float* out = (float*)d_out;

    k_one<<<NBLK, 512, 0, stream>>>(src, trgt, slots, out);
}

// Round 14
// 20.670 us; speedup vs baseline: 1.2765x; 1.2765x over previous
//
#include <hip/hip_runtime.h>

#define NS 384
#define NT 384
#define D  256
#define NTILE 24           // 16-row t-tiles
#define FXP 1048576.0      // 2^20 fixed point

typedef __attribute__((ext_vector_type(8))) short bf16x8;
typedef __attribute__((ext_vector_type(4))) float f32x4;

__device__ __forceinline__ unsigned short f2bf(float f) {   // RNE f32 -> bf16
    unsigned u = __float_as_uint(f);
    return (unsigned short)((u + 0x7FFFu + ((u >> 16) & 1u)) >> 16);
}
__device__ __forceinline__ float bf2f(unsigned short h) {
    return __uint_as_float(((unsigned)h) << 16);
}
// 8 consecutive f32 -> bf16x8 frag; accumulates sum of squares of ROUNDED values
__device__ __forceinline__ bf16x8 load8_bf(const float* __restrict__ p, float& ss) {
    const float4 f0 = *(const float4*)p;
    const float4 f1 = *(const float4*)(p + 4);
    const float vf[8] = {f0.x, f0.y, f0.z, f0.w, f1.x, f1.y, f1.z, f1.w};
    bf16x8 r;
#pragma unroll
    for (int j = 0; j < 8; ++j) {
        const unsigned short h = f2bf(vf[j]);
        r[j] = (short)h;
        const float v = bf2f(h);
        ss += v * v;
    }
    return r;
}
__device__ __forceinline__ float wave_sum64(float v) {
#pragma unroll
    for (int off = 32; off; off >>= 1) v += __shfl_xor(v, off, 64);
    return v;
}

// Node A: 144 blocks = (tile 0..23) x (sl 0..5). Wave w = one 16x16 (t,i)
// MFMA tile (i0 = sl*64 + w*16). Minimal chain: in-register bf16 cast ->
// dot MFMA -> rn -> rnb store. No LDS, no __syncthreads. Designated blocks
// also emit srcT (tile==0), ns2 (tile==0), nt2 (sl==0), group Grams Hq
// (tile==sl). Block 0 resets the fixed-point accumulator.
__global__ __launch_bounds__(256) void k_a(
        const float* __restrict__ src, const float* __restrict__ trgt,
        unsigned short* __restrict__ rnb, unsigned short* __restrict__ srcT,
        float* __restrict__ ns2g, float* __restrict__ nt2g,
        float* __restrict__ Hq,
        unsigned long long* __restrict__ llsum, unsigned* __restrict__ cnt) {
    const int b    = blockIdx.x;
    const int tile = b % NTILE;
    const int sl   = b / NTILE;
    const int tid  = threadIdx.x;
    const int w = tid >> 6, l = tid & 63;
    const int lc = l & 15, lr4 = l >> 4;
    if (b == 0 && tid == 0) { *llsum = 0ull; *cnt = 0u; }

    const int T0 = tile * 16;
    const int i0 = sl * 64 + w * 16;
    const int j  = sl * 4 + w;                     // i-tile index 0..23

    bf16x8 at[8]; float nt2p = 0.f;                // trgt frags + rounded norm
#pragma unroll
    for (int kk = 0; kk < 8; ++kk)
        at[kk] = load8_bf(&trgt[(T0 + lc) * D + kk * 32 + lr4 * 8], nt2p);
    nt2p += __shfl_xor(nt2p, 16, 64);
    nt2p += __shfl_xor(nt2p, 32, 64);              // lane: nt2 of t-row lc

    bf16x8 bs[8]; float ns2p = 0.f;                // src frags + rounded norm
#pragma unroll
    for (int kk = 0; kk < 8; ++kk)
        bs[kk] = load8_bf(&src[(i0 + lc) * D + kk * 32 + lr4 * 8], ns2p);
    ns2p += __shfl_xor(ns2p, 16, 64);
    ns2p += __shfl_xor(ns2p, 32, 64);              // lane: ns2 of src-row lc

    f32x4 acc = {0.f, 0.f, 0.f, 0.f};              // dot[t-row][i-col]
#pragma unroll
    for (int kk = 0; kk < 8; ++kk)
        acc = __builtin_amdgcn_mfma_f32_16x16x32_bf16(at[kk], bs[kk], acc, 0, 0, 0);

#pragma unroll
    for (int r = 0; r < 4; ++r) {
        const int ri = lr4 * 4 + r;
        const float nt2v = __shfl(nt2p, ri, 64);   // lane ri holds row ri's norm
        const float n2 = nt2v + ns2p - 2.f * acc[r];   // norms ~22, EPS never binds
        rnb[(T0 + ri) * NS + i0 + lc] = f2bf(rsqrtf(n2));
    }

    if (tile == 0) {                               // 6 blocks cover all i
#pragma unroll
        for (int kk = 0; kk < 8; ++kk)
#pragma unroll
            for (int jj = 0; jj < 8; ++jj) {
                const int d = kk * 32 + lr4 * 8 + jj;
                srcT[d * NS + i0 + lc] = (unsigned short)bs[kk][jj];
            }
        if (lr4 == 0) ns2g[i0 + lc] = ns2p;        // lanes 0..15, one per row
    }
    if (sl == 0 && w == 0 && lr4 == 0) nt2g[T0 + lc] = nt2p;

    if (tile == sl) {                              // Gram of i-tile j (once grid-wide)
        f32x4 g = {0.f, 0.f, 0.f, 0.f};
#pragma unroll
        for (int kk = 0; kk < 8; ++kk)
            g = __builtin_amdgcn_mfma_f32_16x16x32_bf16(bs[kk], bs[kk], g, 0, 0, 0);
        if (lr4 == (lc >> 2)) {                    // lanes holding diag 4x4 blocks
            const int gg = j * 4 + lr4;            // global group id
#pragma unroll
            for (int r = 0; r < 4; ++r)
                Hq[gg * 16 + r * 4 + (lc & 3)] = g[r];   // Hq[gg][a][c], f32 exact
        }
    }
}

// Node B: 96 blocks = (tile) x (dsl 0..3). W-GEMM (K=384) from rnb/srcT;
// At via ones-operand MFMA (every lane gets its rows' At, no LDS); group
// terms reconstructed from rnb + ns2/nt2 + Hq (dot = (nt2+ns2-1/rn^2)/2,
// error ~1e-7 on loss); loss epilogue vs f32 trgt; fixed-point finish.
__global__ __launch_bounds__(256) void k_b(
        const float* __restrict__ trgt,
        const unsigned short* __restrict__ rnb,
        const unsigned short* __restrict__ srcT,
        const float* __restrict__ ns2g, const float* __restrict__ nt2g,
        const float* __restrict__ Hq,
        unsigned long long* __restrict__ llsum, unsigned* __restrict__ cnt,
        float* __restrict__ out) {
    const int b = blockIdx.x;
    const int tile = b >> 2, dsl = b & 3;
    const int tid = threadIdx.x, w = tid >> 6, l = tid & 63;
    const int lc = l & 15, lr4 = l >> 4;
    const int T0 = tile * 16;
    const int c0 = dsl * 64 + w * 16;              // wave's d-col base

    __shared__ float LossP[4][16], GrpP[4];

    bf16x8 afW[12];                                // rn A-frags (K=384)
#pragma unroll
    for (int kk = 0; kk < 12; ++kk)
        afW[kk] = *(const bf16x8*)&rnb[(T0 + lc) * NS + kk * 32 + lr4 * 8];

    f32x4 wacc = {0.f, 0.f, 0.f, 0.f};             // W[t][c0+lc]
#pragma unroll
    for (int kk = 0; kk < 12; ++kk) {
        const bf16x8 bf = *(const bf16x8*)&srcT[(c0 + lc) * NS + kk * 32 + lr4 * 8];
        wacc = __builtin_amdgcn_mfma_f32_16x16x32_bf16(afW[kk], bf, wacc, 0, 0, 0);
    }
    const short one = 0x3F80;                      // bf16 1.0
    const bf16x8 onesf = {one, one, one, one, one, one, one, one};
    f32x4 aacc = {0.f, 0.f, 0.f, 0.f};             // At[t] in all cols
#pragma unroll
    for (int kk = 0; kk < 12; ++kk)
        aacc = __builtin_amdgcn_mfma_f32_16x16x32_bf16(afW[kk], onesf, aacc, 0, 0, 0);

    // ---- group terms for this dsl's 24 groups x 16 t-rows (384 instances) --
    float gsum = 0.f;
#pragma unroll
    for (int pass = 0; pass < 2; ++pass) {
        const int inst = tid + pass * 256;
        if (inst < 384) {
            const int gl = inst >> 4, t_row = inst & 15;
            const int gg = dsl * 24 + gl;          // global group id
            const int ib = 4 * gg;
            const int t  = T0 + t_row;
            const ushort4 rq = *(const ushort4*)&rnb[t * NS + ib];
            const float4 nsq = *(const float4*)&ns2g[ib];
            const float  nt  = nt2g[t];
            const float r0 = bf2f(rq.x), r1 = bf2f(rq.y);
            const float r2 = bf2f(rq.z), r3 = bf2f(rq.w);
            const float d0 = 0.5f * (nt + nsq.x - 1.f / (r0 * r0));
            const float d1 = 0.5f * (nt + nsq.y - 1.f / (r1 * r1));
            const float d2 = 0.5f * (nt + nsq.z - 1.f / (r2 * r2));
            const float d3 = 0.5f * (nt + nsq.w - 1.f / (r3 * r3));
            const float R = r0 + r1 + r2 + r3;
            const float P = r0 * d0 + r1 * d1 + r2 * d2 + r3 * d3;
            const float4 h0 = *(const float4*)&Hq[gg * 16 + 0];
            const float4 h1 = *(const float4*)&Hq[gg * 16 + 4];
            const float4 h2 = *(const float4*)&Hq[gg * 16 + 8];
            const float4 h3 = *(const float4*)&Hq[gg * 16 + 12];
            const float quad =
                r0 * (h0.x * r0 + h0.y * r1 + h0.z * r2 + h0.w * r3) +
                r1 * (h1.x * r0 + h1.y * r1 + h1.z * r2 + h1.w * r3) +
                r2 * (h2.x * r0 + h2.y * r1 + h2.z * r2 + h2.w * r3) +
                r3 * (h3.x * r0 + h3.y * r1 + h3.z * r2 + h3.w * r3);
            gsum += nt * R * R - 2.f * R * P + quad;   // ||S_g||^2
        }
    }
    gsum = wave_sum64(gsum);
    if (l == 0) GrpP[w] = gsum;

    // ---- loss rows: ||At*t - W||^2 over this wave's 16 cols ----
#pragma unroll
    for (int r = 0; r < 4; ++r) {
        const int ri = lr4 * 4 + r;
        const float tf = trgt[(T0 + ri) * D + c0 + lc];    // f32 exact
        const float S = aacc[r] * tf - wacc[r];
        float v = S * S;
        v += __shfl_xor(v, 1, 64); v += __shfl_xor(v, 2, 64);
        v += __shfl_xor(v, 4, 64); v += __shfl_xor(v, 8, 64);
        if (lc == 0) LossP[w][ri] = v;
    }
    __syncthreads();

    if (tid == 0) {
        double tot = 0.0;
#pragma unroll
        for (int t = 0; t < 16; ++t)
            tot += (double)(LossP[0][t] + LossP[1][t] + LossP[2][t] + LossP[3][t]);
        tot -= 2.0 * (double)(GrpP[0] + GrpP[1] + GrpP[2] + GrpP[3]);
        const long long ll = llrint(tot * FXP);
        atomicAdd(llsum, (unsigned long long)ll);
        __threadfence();
        const unsigned old = atomicAdd(cnt, 1u);
        if (old == NTILE * 4 - 1) {
            const unsigned long long sv = atomicAdd(llsum, 0ull);
            const double total = (double)(long long)sv / FXP;
            out[0] = (float)(total / ((double)NS * (double)NS * (double)NT));
        }
    }
}

extern "C" void kernel_launch(void* const* d_in, const int* in_sizes, int n_in,
                              void* d_out, int out_size, void* d_ws, size_t ws_size,
                              hipStream_t stream) {
    const float* src  = (const float*)d_in[0];   // [384,256] f32
    const float* trgt = (const float*)d_in[1];   // [384,256] f32

    unsigned long long* llsum = (unsigned long long*)d_ws;
    unsigned* cnt = (unsigned*)(llsum + 1);
    unsigned short* rnb  = (unsigned short*)((char*)d_ws + 16);   // [384][384]
    unsigned short* srcT = rnb + (size_t)NT * NS;                 // [256][384]
    float* ns2g = (float*)(srcT + (size_t)D * NS);                // [384]
    float* nt2g = ns2g + NS;                                      // [384]
    float* Hq   = nt2g + NT;                                      // [96][16]
    float* out  = (float*)d_out;

    k_a<<<NTILE * 6, 256, 0, stream>>>(src, trgt, rnb, srcT, ns2g, nt2g, Hq,
                                       llsum, cnt);
    k_b<<<NTILE * 4, 256, 0, stream>>>(trgt, rnb, srcT, ns2g, nt2g, Hq,
                                       llsum, cnt, out);
}